// Round 8
// baseline (158.667 us; speedup 1.0000x reference)
//
#include <hip/hip_runtime.h>
#include <math.h>

#define G 16
#define HS2 400         // hbuf row stride (bf16 elems): 800 B/row
#define LSTR 232        // latb row stride (bf16): 464 B, 16B-aligned, 2-way-bank only

typedef __attribute__((ext_vector_type(8))) __bf16 bf16x8;
typedef __attribute__((ext_vector_type(4))) float f32x4;
typedef __attribute__((ext_vector_type(2))) float f32x2;

// ---------------- Fused kernel: one block = 16 samples, 512 threads = 8 waves ----------------
// 1024 blocks x 8 waves = 32 waves/CU at t=0 (full residency). Phases 0-2 wave-local
// (wave wv owns samples wv*2, wv*2+1). Phase 1 runs ALL 64 lanes (full exec mask for every
// shuffle — r6's divergent-shuffle nondeterminism fix, r7-proven). Phase 3 loads w_fc
// DIRECTLY in B-fragment order with in-register fp32->bf16 cvt (no pre-swizzle kernel).
// 2 barriers total.
__global__ __launch_bounds__(512, 8) void fused_kernel(
    const float* __restrict__ x, const float* __restrict__ params,
    const float* __restrict__ w_fc,
    const float* __restrict__ w_lat, const float* __restrict__ b_lat,
    const float* __restrict__ b_fc,
    const float* __restrict__ w_d1, const float* __restrict__ b_d1,
    const float* __restrict__ w_d2, const float* __restrict__ b_d2,
    float* __restrict__ out, int B)
{
  __shared__ __align__(16) __bf16 latb[G * LSTR];   // 7424 B
  __shared__ __align__(16) __bf16 hbuf[G * HS2];    // 12800 B (bf16: r6-initial-check-proven numerics)
  __shared__ __align__(16) float qfs[G * 4];        // means, then <Z_q>; wave-private regions
  __shared__ float wd1[128];
  __shared__ float wd2[16];
  __shared__ float bd1[4];
  const int t = threadIdx.x;
  const int wv = t >> 6;         // 0..7
  const int lane = t & 63;
  const int s0g = blockIdx.x * G;
  if (s0g >= B) return;

  if (t < 128) wd1[t] = w_d1[t];
  else if (t < 144) wd2[t - 128] = w_d2[t - 128];
  else if (t < 148) bd1[t - 144] = b_d1[t - 144];

  // ---- Phase 0 (wave-local): quadrant sums for samples wv*2, wv*2+1.
  // Issue all 8 dwordx4 loads up-front before consuming (flight depth).
  {
    const float* xb = x + (size_t)(s0g + wv * 2) * 784;
    f32x4 vb[2][4];
    #pragma unroll
    for (int smp = 0; smp < 2; ++smp)
      #pragma unroll
      for (int it = 0; it < 4; ++it) {
        int i4 = lane + it * 64;
        if (i4 < 196)
          vb[smp][it] = __builtin_nontemporal_load((const f32x4*)(xb + smp * 784 + i4 * 4));
        else
          vb[smp][it] = (f32x4){0.f, 0.f, 0.f, 0.f};
      }
    float acc[2][4];   // [smp][quad: TL,TR,BL,BR]
    #pragma unroll
    for (int i = 0; i < 2; ++i)
      #pragma unroll
      for (int q = 0; q < 4; ++q) acc[i][q] = 0.f;
    #pragma unroll
    for (int it = 0; it < 4; ++it) {
      int i4 = lane + it * 64;
      int base = i4 * 4;
      int r = base / 28;
      int cb = base - r * 28;          // float4 never crosses a row (28 % 4 == 0)
      float bt = (r >= 14) ? 1.f : 0.f;
      float tp = 1.f - bt;             // i4 >= 196 lanes loaded zeros, weights irrelevant
      float w0[4], w1[4], w2[4], w3[4];
      #pragma unroll
      for (int e = 0; e < 4; ++e) {
        float lf = ((cb + e) < 14) ? 1.f : 0.f;
        float rf = 1.f - lf;
        w0[e] = tp * lf; w1[e] = tp * rf; w2[e] = bt * lf; w3[e] = bt * rf;
      }
      #pragma unroll
      for (int smp = 0; smp < 2; ++smp) {
        f32x4 v = vb[smp][it];
        #pragma unroll
        for (int e = 0; e < 4; ++e) {
          acc[smp][0] = fmaf(v[e], w0[e], acc[smp][0]);
          acc[smp][1] = fmaf(v[e], w1[e], acc[smp][1]);
          acc[smp][2] = fmaf(v[e], w2[e], acc[smp][2]);
          acc[smp][3] = fmaf(v[e], w3[e], acc[smp][3]);
        }
      }
    }
    #pragma unroll
    for (int smp = 0; smp < 2; ++smp)
      #pragma unroll
      for (int q = 0; q < 4; ++q)
        #pragma unroll
        for (int o = 32; o > 0; o >>= 1)
          acc[smp][q] += __shfl_down(acc[smp][q], o, 64);
    if (lane == 0) {
      const float inv = 1.f / 196.f;
      #pragma unroll
      for (int smp = 0; smp < 2; ++smp) {
        float4 o;
        o.x = acc[smp][0] * inv; o.y = acc[smp][1] * inv;
        o.z = acc[smp][2] * inv; o.w = acc[smp][3] * inv;
        *(float4*)(qfs + (wv * 2 + smp) * 4) = o;
      }
    }
  }
  // no barrier: phases 0-2 stay within the wave (DS ops are in-order per wave)

  // ---- Phase 1 (wave-local, lane-parallel, ALL 64 lanes): 16 lanes per sample;
  // lane-groups 2,3 duplicate groups 0,1 so shuffles run with full exec mask.
  {
    const int sub = lane >> 4;          // 0..3
    const int i   = lane & 15;          // amplitude index; qubit q <-> bit (3-q)
    const int s   = wv * 2 + (sub & 1); // groups 0/2 -> sample 0, 1/3 -> sample 1
    float4 mn = *(const float4*)(qfs + s * 4);
    float c_[4], s_[4];
    c_[0] = __cosf(0.5f * mn.x); s_[0] = __sinf(0.5f * mn.x);
    c_[1] = __cosf(0.5f * mn.y); s_[1] = __sinf(0.5f * mn.y);
    c_[2] = __cosf(0.5f * mn.z); s_[2] = __sinf(0.5f * mn.z);
    c_[3] = __cosf(0.5f * mn.w); s_[3] = __sinf(0.5f * mn.w);
    float re = (((i >> 3) & 1) ? s_[0] : c_[0]) * (((i >> 2) & 1) ? s_[1] : c_[1])
             * (((i >> 1) & 1) ? s_[2] : c_[2]) * ((i & 1) ? s_[3] : c_[3]);
    float im = 0.f;
    #pragma unroll
    for (int q = 0; q < 4; ++q) {
      float hp = 0.5f * params[q];
      float sp = __sinf(hp), cp = __cosf(hp);
      int qb = 3 - q;
      float sg = ((i >> qb) & 1) ? sp : -sp;     // exp(+-i p/2)
      float r0 = re, i0 = im;
      re = r0 * cp - i0 * sg;
      im = r0 * sg + i0 * cp;
      int cm = 1 << qb;
      int tm = 1 << (3 - ((q + 1) & 3));
      int srcI = (i & cm) ? (i ^ tm) : i;        // CNOT: new[i] = old[i^tm] if control set
      int srcLane = (lane & ~15) | srcI;
      re = __shfl(re, srcLane, 64);
      im = __shfl(im, srcLane, 64);
    }
    float p = re * re + im * im;
    float z[4];
    #pragma unroll
    for (int q = 0; q < 4; ++q) {
      int qb = 3 - q;
      float v = ((i >> qb) & 1) ? -p : p;
      v += __shfl_xor(v, 1, 16);
      v += __shfl_xor(v, 2, 16);
      v += __shfl_xor(v, 4, 16);
      v += __shfl_xor(v, 8, 16);
      z[q] = v;
    }
    if (sub < 2 && i < 4) {             // guard only the write; shuffles are done
      float zv = (i == 0) ? z[0] : (i == 1) ? z[1] : (i == 2) ? z[2] : z[3];
      qfs[s * 4 + i] = zv;
    }
  }

  // ---- Phase 2 (wave-local): latent[s][j] = relu(qf[s] . w_lat[j] + b_lat[j]) -> bf16 LDS
  #pragma unroll
  for (int sl = 0; sl < 2; ++sl) {
    int s = wv * 2 + sl;
    float4 q4 = *(const float4*)(qfs + s * 4);
    for (int j = lane; j < 224; j += 64) {
      float4 w = *(const float4*)(w_lat + j * 4);
      float a = b_lat[j];
      a = fmaf(q4.x, w.x, a);
      a = fmaf(q4.y, w.y, a);
      a = fmaf(q4.z, w.z, a);
      a = fmaf(q4.w, w.w, a);
      latb[s * LSTR + j] = (__bf16)fmaxf(a, 0.f);
    }
  }
  __syncthreads();

  // ---- Phase 3: MFMA. wave wv handles N-tiles wv, wv+8, wv+16, (wv+24).
  // B-fragments loaded straight from w_fc (L2-hot, 16 rows/load) + fp32->bf16 cvt.
  {
    const int m = lane & 15;       // A-row (sample) AND B/D-col (n) index
    const int kq = lane >> 4;      // k-quad
    const __bf16* arow = latb + m * LSTR + kq * 8;
    for (int tile = wv; tile < 25; tile += 8) {
      int n = tile * 16 + m;
      bool valid = n < 392;        // tile 24 pads N 392->400
      const float* wr = w_fc + (size_t)n * 224 + kq * 8;
      f32x4 acc = {0.f, 0.f, 0.f, 0.f};
      #pragma unroll
      for (int kt = 0; kt < 7; ++kt) {
        f32x4 blo, bhi;
        if (valid) {
          blo = *(const f32x4*)(wr + kt * 32);
          bhi = *(const f32x4*)(wr + kt * 32 + 4);
        } else {
          blo = (f32x4){0.f, 0.f, 0.f, 0.f};
          bhi = (f32x4){0.f, 0.f, 0.f, 0.f};
        }
        bf16x8 b;
        b[0] = (__bf16)blo[0]; b[1] = (__bf16)blo[1];
        b[2] = (__bf16)blo[2]; b[3] = (__bf16)blo[3];
        b[4] = (__bf16)bhi[0]; b[5] = (__bf16)bhi[1];
        b[6] = (__bf16)bhi[2]; b[7] = (__bf16)bhi[3];
        bf16x8 a = *(const bf16x8*)(arow + kt * 32);
        acc = __builtin_amdgcn_mfma_f32_16x16x32_bf16(a, b, acc, 0, 0, 0);
      }
      int j = tile * 16 + m;
      if (j < 392) {
        float bf = b_fc[j];
        #pragma unroll
        for (int r = 0; r < 4; ++r)
          hbuf[(kq * 4 + r) * HS2 + j] = (__bf16)fmaxf(acc[r] + bf, 0.f);
      }
    }
  }
  __syncthreads();

  // ---- Phase 4: deconv1(8->4, k=s=2) + relu + deconv2(4->1, k=s=2) + sigmoid.
  const float bd2v = b_d2[0];
  for (int v = t; v < G * 196; v += 512) {
    int s = v / 196;
    int p = v - s * 196;
    int Y = p / 14;
    int X = p - Y * 14;
    int y = Y >> 1, ey = Y & 1, xx = X >> 1, ex = X & 1;
    const __bf16* hs = hbuf + s * HS2 + y * 7 + xx;
    float hv[8];
    #pragma unroll
    for (int ci = 0; ci < 8; ++ci) hv[ci] = (float)hs[ci * 49];
    float o1[4];
    #pragma unroll
    for (int co = 0; co < 4; ++co) {
      float a = bd1[co];
      #pragma unroll
      for (int ci = 0; ci < 8; ++ci)
        a = fmaf(hv[ci], wd1[ci * 16 + co * 4 + ey * 2 + ex], a);
      o1[co] = fmaxf(a, 0.f);
    }
    size_t basep = (size_t)(s0g + s) * 784;
    #pragma unroll
    for (int dy = 0; dy < 2; ++dy) {
      float v0 = bd2v, v1 = bd2v;
      #pragma unroll
      for (int co = 0; co < 4; ++co) {
        v0 = fmaf(o1[co], wd2[co * 4 + dy * 2 + 0], v0);
        v1 = fmaf(o1[co], wd2[co * 4 + dy * 2 + 1], v1);
      }
      f32x2 o;
      o[0] = 1.f / (1.f + __expf(-v0));
      o[1] = 1.f / (1.f + __expf(-v1));
      __builtin_nontemporal_store(o, (f32x2*)(out + basep + (size_t)(2 * Y + dy) * 28 + 2 * X));
    }
  }
}

extern "C" void kernel_launch(void* const* d_in, const int* in_sizes, int n_in,
                              void* d_out, int out_size, void* d_ws, size_t ws_size,
                              hipStream_t stream) {
  const float* x          = (const float*)d_in[0];
  const float* var_params = (const float*)d_in[1];
  const float* w_lat      = (const float*)d_in[2];
  const float* b_lat      = (const float*)d_in[3];
  const float* w_fc       = (const float*)d_in[4];
  const float* b_fc       = (const float*)d_in[5];
  const float* w_d1       = (const float*)d_in[6];
  const float* b_d1       = (const float*)d_in[7];
  const float* w_d2       = (const float*)d_in[8];
  const float* b_d2       = (const float*)d_in[9];
  float* out = (float*)d_out;
  (void)d_ws; (void)ws_size;

  int B = in_sizes[0] / 784;
  fused_kernel<<<(B + G - 1) / G, 512, 0, stream>>>(
      x, var_params, w_fc, w_lat, b_lat, b_fc, w_d1, b_d1, w_d2, b_d2, out, B);
}

// Round 9
// 134.747 us; speedup vs baseline: 1.1775x; 1.1775x over previous
//
#include <hip/hip_runtime.h>
#include <math.h>

#define G 16
#define HS2 400         // hbuf row stride (bf16 elems): 800 B/row
#define LSTR 232        // latb row stride (bf16): 464 B, 16B-aligned, 2-way-bank only

typedef __attribute__((ext_vector_type(8))) __bf16 bf16x8;
typedef __attribute__((ext_vector_type(4))) float f32x4;
typedef __attribute__((ext_vector_type(2))) float f32x2;

// ---------------- Kernel W: swizzle w_fc (392x224 fp32) into bf16 MFMA B-fragments ----------
// wb[((tile*7 + kt)*64 + lane)*8 + j] = bf16(w_fc[n][k]), n = tile*16 + (lane&15),
// k = kt*32 + (lane>>4)*8 + j.  Tiles 0..24 (N padded 392->400 with zeros).
// This costs one ~2 µs launch but makes every phase-3 B-read a single contiguous
// 1 KB wave transaction — r8 proved dropping it costs ~30 µs in uncoalesced L2 traffic.
__global__ void wconv_kernel(const float* __restrict__ w_fc, __bf16* __restrict__ wb) {
  int tile = blockIdx.x;      // 0..24
  int kt   = blockIdx.y;      // 0..6
  int lane = threadIdx.x;     // 0..63
  int n  = tile * 16 + (lane & 15);
  int k0 = kt * 32 + (lane >> 4) * 8;
  bf16x8 v;
  if (n < 392) {
    const float* src = w_fc + (size_t)n * 224 + k0;
    float4 f0 = *(const float4*)(src);
    float4 f1 = *(const float4*)(src + 4);
    v[0] = (__bf16)f0.x; v[1] = (__bf16)f0.y; v[2] = (__bf16)f0.z; v[3] = (__bf16)f0.w;
    v[4] = (__bf16)f1.x; v[5] = (__bf16)f1.y; v[6] = (__bf16)f1.z; v[7] = (__bf16)f1.w;
  } else {
    #pragma unroll
    for (int j = 0; j < 8; ++j) v[j] = (__bf16)0.f;
  }
  *(bf16x8*)(wb + ((size_t)(tile * 7 + kt) * 64 + lane) * 8) = v;
}

// ---------------- Fused kernel: one block = 16 samples, 512 threads = 8 waves ----------------
// 1024 blocks x 8 waves = 32 waves/CU at t=0 (full residency). Phases 0-2 wave-local
// (wave wv owns samples wv*2, wv*2+1). Phase 1 runs ALL 64 lanes (full exec mask for every
// shuffle — r6's divergent-shuffle nondeterminism fix, r7/r8-proven). 2 barriers total.
__global__ __launch_bounds__(512, 8) void fused_kernel(
    const float* __restrict__ x, const float* __restrict__ params,
    const __bf16* __restrict__ wb,
    const float* __restrict__ w_lat, const float* __restrict__ b_lat,
    const float* __restrict__ b_fc,
    const float* __restrict__ w_d1, const float* __restrict__ b_d1,
    const float* __restrict__ w_d2, const float* __restrict__ b_d2,
    float* __restrict__ out, int B)
{
  __shared__ __align__(16) __bf16 latb[G * LSTR];   // 7424 B
  __shared__ __align__(16) __bf16 hbuf[G * HS2];    // 12800 B (bf16: r8-proven numerics+determinism)
  __shared__ __align__(16) float qfs[G * 4];        // means, then <Z_q>; wave-private regions
  __shared__ float wd1[128];
  __shared__ float wd2[16];
  __shared__ float bd1[4];
  const int t = threadIdx.x;
  const int wv = t >> 6;         // 0..7
  const int lane = t & 63;
  const int s0g = blockIdx.x * G;
  if (s0g >= B) return;

  if (t < 128) wd1[t] = w_d1[t];
  else if (t < 144) wd2[t - 128] = w_d2[t - 128];
  else if (t < 148) bd1[t - 144] = b_d1[t - 144];

  // ---- Phase 0 (wave-local): quadrant sums for samples wv*2, wv*2+1.
  // Issue all 8 dwordx4 loads up-front before consuming (flight depth).
  {
    const float* xb = x + (size_t)(s0g + wv * 2) * 784;
    f32x4 vb[2][4];
    #pragma unroll
    for (int smp = 0; smp < 2; ++smp)
      #pragma unroll
      for (int it = 0; it < 4; ++it) {
        int i4 = lane + it * 64;
        if (i4 < 196)
          vb[smp][it] = __builtin_nontemporal_load((const f32x4*)(xb + smp * 784 + i4 * 4));
        else
          vb[smp][it] = (f32x4){0.f, 0.f, 0.f, 0.f};
      }
    float acc[2][4];   // [smp][quad: TL,TR,BL,BR]
    #pragma unroll
    for (int i = 0; i < 2; ++i)
      #pragma unroll
      for (int q = 0; q < 4; ++q) acc[i][q] = 0.f;
    #pragma unroll
    for (int it = 0; it < 4; ++it) {
      int i4 = lane + it * 64;
      int base = i4 * 4;
      int r = base / 28;
      int cb = base - r * 28;          // float4 never crosses a row (28 % 4 == 0)
      float bt = (r >= 14) ? 1.f : 0.f;
      float tp = 1.f - bt;             // i4 >= 196 lanes loaded zeros, weights irrelevant
      float w0[4], w1[4], w2[4], w3[4];
      #pragma unroll
      for (int e = 0; e < 4; ++e) {
        float lf = ((cb + e) < 14) ? 1.f : 0.f;
        float rf = 1.f - lf;
        w0[e] = tp * lf; w1[e] = tp * rf; w2[e] = bt * lf; w3[e] = bt * rf;
      }
      #pragma unroll
      for (int smp = 0; smp < 2; ++smp) {
        f32x4 v = vb[smp][it];
        #pragma unroll
        for (int e = 0; e < 4; ++e) {
          acc[smp][0] = fmaf(v[e], w0[e], acc[smp][0]);
          acc[smp][1] = fmaf(v[e], w1[e], acc[smp][1]);
          acc[smp][2] = fmaf(v[e], w2[e], acc[smp][2]);
          acc[smp][3] = fmaf(v[e], w3[e], acc[smp][3]);
        }
      }
    }
    #pragma unroll
    for (int smp = 0; smp < 2; ++smp)
      #pragma unroll
      for (int q = 0; q < 4; ++q)
        #pragma unroll
        for (int o = 32; o > 0; o >>= 1)
          acc[smp][q] += __shfl_down(acc[smp][q], o, 64);
    if (lane == 0) {
      const float inv = 1.f / 196.f;
      #pragma unroll
      for (int smp = 0; smp < 2; ++smp) {
        float4 o;
        o.x = acc[smp][0] * inv; o.y = acc[smp][1] * inv;
        o.z = acc[smp][2] * inv; o.w = acc[smp][3] * inv;
        *(float4*)(qfs + (wv * 2 + smp) * 4) = o;
      }
    }
  }
  // no barrier: phases 0-2 stay within the wave (DS ops are in-order per wave)

  // ---- Phase 1 (wave-local, lane-parallel, ALL 64 lanes): 16 lanes per sample;
  // lane-groups 2,3 duplicate groups 0,1 so shuffles run with full exec mask.
  {
    const int sub = lane >> 4;          // 0..3
    const int i   = lane & 15;          // amplitude index; qubit q <-> bit (3-q)
    const int s   = wv * 2 + (sub & 1); // groups 0/2 -> sample 0, 1/3 -> sample 1
    float4 mn = *(const float4*)(qfs + s * 4);
    float c_[4], s_[4];
    c_[0] = __cosf(0.5f * mn.x); s_[0] = __sinf(0.5f * mn.x);
    c_[1] = __cosf(0.5f * mn.y); s_[1] = __sinf(0.5f * mn.y);
    c_[2] = __cosf(0.5f * mn.z); s_[2] = __sinf(0.5f * mn.z);
    c_[3] = __cosf(0.5f * mn.w); s_[3] = __sinf(0.5f * mn.w);
    float re = (((i >> 3) & 1) ? s_[0] : c_[0]) * (((i >> 2) & 1) ? s_[1] : c_[1])
             * (((i >> 1) & 1) ? s_[2] : c_[2]) * ((i & 1) ? s_[3] : c_[3]);
    float im = 0.f;
    #pragma unroll
    for (int q = 0; q < 4; ++q) {
      float hp = 0.5f * params[q];
      float sp = __sinf(hp), cp = __cosf(hp);
      int qb = 3 - q;
      float sg = ((i >> qb) & 1) ? sp : -sp;     // exp(+-i p/2)
      float r0 = re, i0 = im;
      re = r0 * cp - i0 * sg;
      im = r0 * sg + i0 * cp;
      int cm = 1 << qb;
      int tm = 1 << (3 - ((q + 1) & 3));
      int srcI = (i & cm) ? (i ^ tm) : i;        // CNOT: new[i] = old[i^tm] if control set
      int srcLane = (lane & ~15) | srcI;
      re = __shfl(re, srcLane, 64);
      im = __shfl(im, srcLane, 64);
    }
    float p = re * re + im * im;
    float z[4];
    #pragma unroll
    for (int q = 0; q < 4; ++q) {
      int qb = 3 - q;
      float v = ((i >> qb) & 1) ? -p : p;
      v += __shfl_xor(v, 1, 16);
      v += __shfl_xor(v, 2, 16);
      v += __shfl_xor(v, 4, 16);
      v += __shfl_xor(v, 8, 16);
      z[q] = v;
    }
    if (sub < 2 && i < 4) {             // guard only the write; shuffles are done
      float zv = (i == 0) ? z[0] : (i == 1) ? z[1] : (i == 2) ? z[2] : z[3];
      qfs[s * 4 + i] = zv;
    }
  }

  // ---- Phase 2 (wave-local): latent[s][j] = relu(qf[s] . w_lat[j] + b_lat[j]) -> bf16 LDS
  #pragma unroll
  for (int sl = 0; sl < 2; ++sl) {
    int s = wv * 2 + sl;
    float4 q4 = *(const float4*)(qfs + s * 4);
    for (int j = lane; j < 224; j += 64) {
      float4 w = *(const float4*)(w_lat + j * 4);
      float a = b_lat[j];
      a = fmaf(q4.x, w.x, a);
      a = fmaf(q4.y, w.y, a);
      a = fmaf(q4.z, w.z, a);
      a = fmaf(q4.w, w.w, a);
      latb[s * LSTR + j] = (__bf16)fmaxf(a, 0.f);
    }
  }
  __syncthreads();

  // ---- Phase 3: MFMA. wave wv handles N-tiles wv, wv+8, wv+16, (wv+24).
  // B streamed from pre-swizzled wb: one contiguous 1 KB dwordx4 wave-read per (tile,kt).
  {
    const int m = lane & 15;       // A-row (sample) AND B/D-col (n) index
    const int kq = lane >> 4;      // k-quad
    const __bf16* arow = latb + m * LSTR + kq * 8;
    for (int tile = wv; tile < 25; tile += 8) {
      f32x4 acc = {0.f, 0.f, 0.f, 0.f};
      const bf16x8* bp = (const bf16x8*)(wb + ((size_t)(tile * 7) * 64 + lane) * 8);
      #pragma unroll
      for (int kt = 0; kt < 7; ++kt) {
        bf16x8 a = *(const bf16x8*)(arow + kt * 32);
        bf16x8 b = bp[kt * 64];
        acc = __builtin_amdgcn_mfma_f32_16x16x32_bf16(a, b, acc, 0, 0, 0);
      }
      int j = tile * 16 + m;
      if (j < 392) {
        float bf = b_fc[j];
        #pragma unroll
        for (int r = 0; r < 4; ++r)
          hbuf[(kq * 4 + r) * HS2 + j] = (__bf16)fmaxf(acc[r] + bf, 0.f);
      }
    }
  }
  __syncthreads();

  // ---- Phase 4: deconv1(8->4, k=s=2) + relu + deconv2(4->1, k=s=2) + sigmoid.
  const float bd2v = b_d2[0];
  for (int v = t; v < G * 196; v += 512) {
    int s = v / 196;
    int p = v - s * 196;
    int Y = p / 14;
    int X = p - Y * 14;
    int y = Y >> 1, ey = Y & 1, xx = X >> 1, ex = X & 1;
    const __bf16* hs = hbuf + s * HS2 + y * 7 + xx;
    float hv[8];
    #pragma unroll
    for (int ci = 0; ci < 8; ++ci) hv[ci] = (float)hs[ci * 49];
    float o1[4];
    #pragma unroll
    for (int co = 0; co < 4; ++co) {
      float a = bd1[co];
      #pragma unroll
      for (int ci = 0; ci < 8; ++ci)
        a = fmaf(hv[ci], wd1[ci * 16 + co * 4 + ey * 2 + ex], a);
      o1[co] = fmaxf(a, 0.f);
    }
    size_t basep = (size_t)(s0g + s) * 784;
    #pragma unroll
    for (int dy = 0; dy < 2; ++dy) {
      float v0 = bd2v, v1 = bd2v;
      #pragma unroll
      for (int co = 0; co < 4; ++co) {
        v0 = fmaf(o1[co], wd2[co * 4 + dy * 2 + 0], v0);
        v1 = fmaf(o1[co], wd2[co * 4 + dy * 2 + 1], v1);
      }
      f32x2 o;
      o[0] = 1.f / (1.f + __expf(-v0));
      o[1] = 1.f / (1.f + __expf(-v1));
      __builtin_nontemporal_store(o, (f32x2*)(out + basep + (size_t)(2 * Y + dy) * 28 + 2 * X));
    }
  }
}

extern "C" void kernel_launch(void* const* d_in, const int* in_sizes, int n_in,
                              void* d_out, int out_size, void* d_ws, size_t ws_size,
                              hipStream_t stream) {
  const float* x          = (const float*)d_in[0];
  const float* var_params = (const float*)d_in[1];
  const float* w_lat      = (const float*)d_in[2];
  const float* b_lat      = (const float*)d_in[3];
  const float* w_fc       = (const float*)d_in[4];
  const float* b_fc       = (const float*)d_in[5];
  const float* w_d1       = (const float*)d_in[6];
  const float* b_d1       = (const float*)d_in[7];
  const float* w_d2       = (const float*)d_in[8];
  const float* b_d2       = (const float*)d_in[9];
  float* out = (float*)d_out;

  __bf16* wb = (__bf16*)d_ws;   // 25*7*64*8 bf16 = 179200 B of swizzled w_fc fragments

  int B = in_sizes[0] / 784;
  wconv_kernel<<<dim3(25, 7), 64, 0, stream>>>(w_fc, wb);
  fused_kernel<<<(B + G - 1) / G, 512, 0, stream>>>(
      x, var_params, wb, w_lat, b_lat, b_fc, w_d1, b_d1, w_d2, b_d2, out, B);
}